// Round 1
// baseline (147.154 us; speedup 1.0000x reference)
//
#include <hip/hip_runtime.h>

// x volumes: [256,256,256] fp32. Row (d,h) = 256 floats = 64 float4.
// float4-unit offset: d*16384 + h*64 + lane.
//
// 3-axis stencil decomposition: registers roll the d-axis, LDS holds the
// h-axis (block = 4 waves = 4 computed h-rows + 2 halo rows staged per
// d-plane), __shfl handles the w-axis.
//
// R7 (this round): the per-step __syncthreads() was compiling to
// "s_waitcnt vmcnt(0) lgkmcnt(0); s_barrier" — draining the step's own
// prefetch loads at every barrier, so the advertised depth-2 pipeline never
// existed in the emitted code (L3-resident replays ran at the same 48us as
// cold runs => latency-bound, not BW-bound; VALUBusy 25%).
// Fixes: (1) fence-free barrier (lgkmcnt-only + raw s_barrier) so prefetch
// loads stay in flight across barriers, backend emits counted vmcnt(N) at
// the staging ds_write instead; (2) register pipeline deepened to planes
// a/b/c/p so the staged plane was loaded 2 full steps earlier; (3) D_CHUNK
// 4->8 to halve full-latency prologues.
// R4-R6 lesson: keep VMEM at 3 f4 loads/wave-step, no sparse edge loads.
// R3 lesson: no __threadfence / fused finalize (per-XCD L2 writeback storm).
//
// Grid: 64 htiles x 32 d-chunks (8 deep) = 2048 blocks x 256 thr, 24 KB LDS.

#define D_CHUNK 8

__device__ __forceinline__ void sync_lds_only() {
    // LDS-visibility barrier WITHOUT the vmcnt(0) drain __syncthreads() emits:
    // each wave waits its own ds_writes (lgkmcnt), then hits a raw s_barrier.
    // Global loads in flight cross the barrier untouched; the backend waits
    // them with counted vmcnt(N) at their first use (the next staging write).
    asm volatile("s_waitcnt lgkmcnt(0)" ::: "memory");
    __builtin_amdgcn_s_barrier();
}

__global__ __launch_bounds__(256) void grad_loss_kernel(const float* __restrict__ xf1,
                                                        const float* __restrict__ xf2,
                                                        double* __restrict__ acc) {
    const float4* __restrict__ x1 = (const float4*)xf1;
    const float4* __restrict__ x2 = (const float4*)xf2;

    // [buf][input][row-slot][lane]; slot s holds row h0-1+s. 24 KB.
    __shared__ float4 plane[2][2][6][64];

    const int tid   = threadIdx.x;
    const int lane  = tid & 63;
    const int wid   = tid >> 6;         // 0..3
    const int htile = blockIdx.x & 63;  // 0..63
    const int dchk  = blockIdx.x >> 6;  // 0..31

    const int h0 = 1 + htile * 4;       // computed rows h0..h0+3 (tail rows >254 dead)
    const int d0 = 1 + dchk * D_CHUNK;  // computed depths d0..d0+7 (tail >254 dead)

    const int  h    = h0 + wid;
    const bool live = (h <= 254);
    const int  hrow = (h <= 255) ? h : 255;       // clamped row for loads

    // halo duty: wave0 -> (h0-1, x1), wave1 -> (h0-1, x2),
    //            wave2 -> (h0+4, x1), wave3 -> (h0+4, x2)   (rows clamped)
    const int halo_row  = (wid < 2) ? (h0 - 1) : ((h0 + 4 <= 255) ? (h0 + 4) : 255);
    const int halo_slot = (wid < 2) ? 0 : 5;
    const int halo_inp  = wid & 1;
    const float4* __restrict__ halo4 = halo_inp ? x2 : x1;

    const int own_f4  = hrow * 64 + lane;
    const int halo_f4 = halo_row * 64 + lane;

    // per-voxel w-axis weights (0 = excluded border, 2 = edge-replicated)
    const float ww0 = (lane == 0)  ? 0.0f : 1.0f;   // w = 4*lane   (w==0)
    const float ww1 = (lane == 0)  ? 2.0f : 1.0f;   // w = 4*lane+1 (w==1)
    const float ww2 = (lane == 63) ? 2.0f : 1.0f;   // w = 4*lane+2 (w==254)
    const float ww3 = (lane == 63) ? 0.0f : 1.0f;   // w = 4*lane+3 (w==255)
    const float whf = (h == 1 || h == 254) ? 2.0f : 1.0f;

    // ---- prologue: depth-3 register pipeline.
    // a=plane(d0-1), b=plane(d0), c=plane(d0+1), p=plane(d0+2) own rows;
    // halos hb (staged now), hc, hp. Issue own/halo loads for b first so the
    // staging ds_write below waits a counted vmcnt, keeping the rest in flight.
    float4 b1 = x1[d0 * 16384 + own_f4];
    float4 b2 = x2[d0 * 16384 + own_f4];
    float4 hb = halo4[d0 * 16384 + halo_f4];
    float4 a1 = x1[(d0 - 1) * 16384 + own_f4];
    float4 a2 = x2[(d0 - 1) * 16384 + own_f4];
    float4 c1 = x1[(d0 + 1) * 16384 + own_f4];     // d0+1 <= 250 always
    float4 c2 = x2[(d0 + 1) * 16384 + own_f4];
    float4 hc = halo4[(d0 + 1) * 16384 + halo_f4];
    const int dp2 = (d0 + 2 <= 255) ? (d0 + 2) : 255;
    float4 p1 = x1[dp2 * 16384 + own_f4];
    float4 p2 = x2[dp2 * 16384 + own_f4];
    float4 hp = halo4[dp2 * 16384 + halo_f4];

    plane[0][0][wid + 1][lane] = b1;
    plane[0][1][wid + 1][lane] = b2;
    plane[0][halo_inp][halo_slot][lane] = hb;
    sync_lds_only();

    float val = 0.0f;

    #pragma unroll
    for (int i = 0; i < D_CHUNK; ++i) {
        const int d   = d0 + i;
        const int cur = i & 1;
        const int nxt = cur ^ 1;
        const int dn  = (d + 3 <= 255) ? (d + 3) : 255;   // prefetch depth (clamped tail)

        // prefetch plane d+3 (consumed 2 steps from now)
        float4 q1 = x1[dn * 16384 + own_f4];
        float4 q2 = x2[dn * 16384 + own_f4];
        float4 hq = halo4[dn * 16384 + halo_f4];

        // stage plane d+1 into LDS[nxt] — c regs were loaded 2 steps ago, so
        // the backend's counted vmcnt here has ~2 steps + 2 barriers of slack
        plane[nxt][0][wid + 1][lane] = c1;
        plane[nxt][1][wid + 1][lane] = c2;
        plane[nxt][halo_inp][halo_slot][lane] = hc;

        // compute depth d from LDS[cur] + a/b/c regs
        if (live && d <= 254) {
            float4 u1 = plane[cur][0][wid][lane];       // row h-1
            float4 v1 = plane[cur][0][wid + 2][lane];   // row h+1
            float4 u2 = plane[cur][1][wid][lane];
            float4 v2 = plane[cur][1][wid + 2][lane];

            float l1 = __shfl_up(b1.w, 1, 64);          // garbage on lane0 -> ww0=0
            float r1 = __shfl_down(b1.x, 1, 64);        // garbage on lane63 -> ww3=0
            float l2 = __shfl_up(b2.w, 1, 64);
            float r2 = __shfl_down(b2.x, 1, 64);

            float gw, gd, gh;
            gw = c1.x - a1.x; gd = v1.x - u1.x; gh = b1.y - l1;
            float m10 = __builtin_amdgcn_sqrtf(gw * gw + gd * gd + gh * gh + 1e-6f);
            gw = c1.y - a1.y; gd = v1.y - u1.y; gh = b1.z - b1.x;
            float m11 = __builtin_amdgcn_sqrtf(gw * gw + gd * gd + gh * gh + 1e-6f);
            gw = c1.z - a1.z; gd = v1.z - u1.z; gh = b1.w - b1.y;
            float m12 = __builtin_amdgcn_sqrtf(gw * gw + gd * gd + gh * gh + 1e-6f);
            gw = c1.w - a1.w; gd = v1.w - u1.w; gh = r1 - b1.z;
            float m13 = __builtin_amdgcn_sqrtf(gw * gw + gd * gd + gh * gh + 1e-6f);

            gw = c2.x - a2.x; gd = v2.x - u2.x; gh = b2.y - l2;
            float m20 = __builtin_amdgcn_sqrtf(gw * gw + gd * gd + gh * gh + 1e-6f);
            gw = c2.y - a2.y; gd = v2.y - u2.y; gh = b2.z - b2.x;
            float m21 = __builtin_amdgcn_sqrtf(gw * gw + gd * gd + gh * gh + 1e-6f);
            gw = c2.z - a2.z; gd = v2.z - u2.z; gh = b2.w - b2.y;
            float m22 = __builtin_amdgcn_sqrtf(gw * gw + gd * gd + gh * gh + 1e-6f);
            gw = c2.w - a2.w; gd = v2.w - u2.w; gh = r2 - b2.z;
            float m23 = __builtin_amdgcn_sqrtf(gw * gw + gd * gd + gh * gh + 1e-6f);

            float inner = ww0 * fabsf(m10 - m20)
                        + ww1 * fabsf(m11 - m21)
                        + ww2 * fabsf(m12 - m22)
                        + ww3 * fabsf(m13 - m23);

            const float wdf = (d == 1 || d == 254) ? 2.0f : 1.0f;
            val += wdf * whf * inner;
        }

        // roll the depth pipeline: a<-b<-c<-p<-q
        a1 = b1; b1 = c1; c1 = p1; p1 = q1;
        a2 = b2; b2 = c2; c2 = p2; p2 = q2;
        hc = hp; hp = hq;

        sync_lds_only();   // plane[nxt] writes visible; plane[cur] reads done
    }

    // wave-64 reduction
    for (int off = 32; off > 0; off >>= 1)
        val += __shfl_down(val, off, 64);

    __shared__ float smem[4];
    if (lane == 0) smem[wid] = val;
    __syncthreads();

    if (wid == 0) {
        float s = (lane < 4) ? smem[lane] : 0.0f;
        s += __shfl_down(s, 2, 64);
        s += __shfl_down(s, 1, 64);
        if (lane == 0)
            atomicAdd(&acc[blockIdx.x & 255], (double)s);   // no fence!
    }
}

__global__ void finalize_kernel(const double* __restrict__ acc, float* __restrict__ out) {
    double v = acc[threadIdx.x];   // 256 threads, one slot each
    for (int off = 32; off > 0; off >>= 1)
        v += __shfl_down(v, off, 64);

    __shared__ double smem[4];
    const int lid = threadIdx.x & 63;
    const int wid = threadIdx.x >> 6;
    if (lid == 0) smem[wid] = v;
    __syncthreads();

    if (threadIdx.x == 0) {
        double s = smem[0] + smem[1] + smem[2] + smem[3];
        out[0] = (float)(s / 16777216.0);   // mean over 256^3
    }
}

extern "C" void kernel_launch(void* const* d_in, const int* in_sizes, int n_in,
                              void* d_out, int out_size, void* d_ws, size_t ws_size,
                              hipStream_t stream) {
    const float* x1 = (const float*)d_in[0];
    const float* x2 = (const float*)d_in[1];
    float* out = (float*)d_out;
    double* acc = (double*)d_ws;   // 256 doubles = 2 KiB scratch

    hipMemsetAsync(d_ws, 0, 256 * sizeof(double), stream);
    grad_loss_kernel<<<64 * 32, 256, 0, stream>>>(x1, x2, acc);
    finalize_kernel<<<1, 256, 0, stream>>>(acc, out);
}